// Round 1
// baseline (606.547 us; speedup 1.0000x reference)
//
#include <hip/hip_runtime.h>
#include <stdint.h>

// Problem constants (also derived from in_sizes at launch)
#define CA 64     // in channels
#define CB 128    // out channels
#define KOFF 27   // 3^3 offsets
#define BN_EPS 1e-4f

typedef short bf16x8 __attribute__((ext_vector_type(8)));      // 8 bf16 = 4 VGPRs (MFMA A/B frag)
typedef float f32x4 __attribute__((ext_vector_type(4)));       // MFMA C/D frag
typedef unsigned int u32x4 __attribute__((ext_vector_type(4)));
typedef unsigned short u16x4 __attribute__((ext_vector_type(4)));

__device__ __forceinline__ unsigned short f2bf(float f) {
  union { float f; uint32_t u; } c; c.f = f;
  uint32_t u = c.u;
  return (unsigned short)((u + 0x7FFFu + ((u >> 16) & 1u)) >> 16);  // RNE
}

// ---- mask dtype detection: if int32 layout, bytes at i%4!=0 are all zero ----
__global__ void detect_mask_k(const unsigned char* __restrict__ m, int* flag) {
  unsigned v = 0;
  for (int i = threadIdx.x; i < 4096; i += 256)
    if (i & 3) v |= m[i];
  if (v) atomicOr(flag, 1);   // 1 => byte/bool layout, 0 => int32 layout
}

__global__ void pack_mask_k(const void* __restrict__ mp, const int* __restrict__ flag,
                            uint32_t* __restrict__ bits, int n) {
  int i = blockIdx.x * blockDim.x + threadIdx.x;
  if (i >= n) return;
  uint32_t b = 0;
  if (*flag) {
    const unsigned char* m = (const unsigned char*)mp + (size_t)i * KOFF;
    for (int k = 0; k < KOFF; k++) b |= (m[k] ? 1u : 0u) << k;
  } else {
    const int* m = (const int*)mp + (size_t)i * KOFF;
    for (int k = 0; k < KOFF; k++) b |= (m[k] ? 1u : 0u) << k;
  }
  bits[i] = b;
}

// ---- weight transpose + bf16 convert: wt[k][co][ci] = bf16(w[k][ci][co]) ----
__global__ void transpose_w_k(const float* __restrict__ w, unsigned short* __restrict__ wt,
                              int K, int Cin, int Cout) {
  int idx = blockIdx.x * blockDim.x + threadIdx.x;
  int total = K * Cin * Cout;
  if (idx >= total) return;
  int ci = idx % Cin;
  int t2 = idx / Cin;
  int co = t2 % Cout;
  int k  = t2 / Cout;
  wt[idx] = f2bf(w[((size_t)k * Cin + ci) * Cout + co]);
}

// ---- per-channel sum & sumsq (training-mode BN stats) ----
template<int C>
__global__ void col_stats_k(const float* __restrict__ x, int n, float* __restrict__ sums) {
  __shared__ float ssum[C], ssq[C];
  int t = threadIdx.x;
  for (int i = t; i < C; i += 256) { ssum[i] = 0.f; ssq[i] = 0.f; }
  __syncthreads();
  const int c = t % C;
  const int rpb = 256 / C;
  float s = 0.f, q = 0.f;
  for (int r = blockIdx.x * rpb + t / C; r < n; r += gridDim.x * rpb) {
    float v = x[(size_t)r * C + c];
    s += v; q += v * v;
  }
  atomicAdd(&ssum[c], s);
  atomicAdd(&ssq[c], q);
  __syncthreads();
  for (int i = t; i < C; i += 256) {
    atomicAdd(&sums[i], ssum[i]);
    atomicAdd(&sums[C + i], ssq[i]);
  }
}

// ---- BN scale/shift: sc[c]=gamma*rstd, sc[C+c]=beta-mean*scale ----
template<int C>
__global__ void bn_finalize_k(const float* __restrict__ sums, const float* __restrict__ gamma,
                              const float* __restrict__ beta, float* __restrict__ sc, int n) {
  int c = threadIdx.x;
  if (c >= C) return;
  float inv_n = 1.f / (float)n;
  float mean = sums[c] * inv_n;
  float var = sums[C + c] * inv_n - mean * mean;
  float rstd = rsqrtf(var + BN_EPS);
  float scale = gamma[c] * rstd;
  sc[c] = scale;
  sc[C + c] = beta[c] - mean * scale;
}

// ---- apply BN + ReLU -> bf16; optionally also raw bf16 cast of input ----
template<int C, bool RAW>
__global__ void bn_apply_k(const float* __restrict__ x, const float* __restrict__ sc,
                           unsigned short* __restrict__ h, unsigned short* __restrict__ raw,
                           int total) {
  int idx = (blockIdx.x * blockDim.x + threadIdx.x) * 4;
  if (idx >= total) return;
  f32x4 v = *(const f32x4*)&x[idx];
  int c0 = idx % C;
  u16x4 ho, ro;
#pragma unroll
  for (int j = 0; j < 4; j++) {
    float s = sc[c0 + j], b = sc[C + c0 + j];
    float hv = fmaxf(v[j] * s + b, 0.f);
    ho[j] = f2bf(hv);
    if (RAW) ro[j] = f2bf(v[j]);
  }
  *(u16x4*)&h[idx] = ho;
  if (RAW) *(u16x4*)&raw[idx] = ro;
}

// ---- gather-GEMM subconv: out[n,:] = sum_k mask[n,k] * hin[nbr[n,k],:] @ W[k]
// Block: 64 rows x 128 cols, 256 threads (4 waves, each 64x32).
// Weights pre-transposed: wt[k][co][ci] so B-frags are contiguous 16B loads.
// FUSE: additionally init acc with fbraw(rows) @ wnt (the NiN shortcut, K=64).
template<int CIN, bool FUSE>
__launch_bounds__(256)
__global__ void conv_k(const unsigned short* __restrict__ hin,
                       const unsigned short* __restrict__ wt,
                       const int* __restrict__ nbr,
                       const uint32_t* __restrict__ mbits,
                       const unsigned short* __restrict__ fbraw,
                       const unsigned short* __restrict__ wnt,
                       float* __restrict__ out, int n) {
  constexpr int TR = 64;
  constexpr int STR = CIN + 8;   // +16B pad breaks LDS bank alias across rows
  constexpr int FSTR = CA + 8;
  __shared__ alignas(16) unsigned short tile[TR * STR];
  __shared__ alignas(16) unsigned short ftile[FUSE ? TR * FSTR : 16];
  __shared__ int lnbr[TR * KOFF];
  __shared__ uint32_t lmb[TR];

  const int t = threadIdx.x;
  const int rowbase = blockIdx.x * TR;
  const int nrows = min(TR, n - rowbase);

  for (int i = t; i < nrows * KOFF; i += 256) lnbr[i] = nbr[(size_t)rowbase * KOFF + i];
  if (t < TR) lmb[t] = (t < nrows) ? mbits[rowbase + t] : 0u;

  if constexpr (FUSE) {
#pragma unroll
    for (int p = 0; p < 2; p++) {
      int r = p * 32 + (t >> 3);
      int ch = (t & 7) * 8;
      u32x4 v = {0, 0, 0, 0};
      if (r < nrows) v = *(const u32x4*)&fbraw[(size_t)(rowbase + r) * CA + ch];
      *(u32x4*)&ftile[r * FSTR + ch] = v;
    }
  }
  __syncthreads();

  const int lane = t & 63;
  const int wave = t >> 6;
  const int l16 = lane & 15;
  const int quad = lane >> 4;
  const int colbase = wave * 32;

  f32x4 zero = {0.f, 0.f, 0.f, 0.f};
  f32x4 acc[4][2];
#pragma unroll
  for (int i = 0; i < 4; i++) { acc[i][0] = zero; acc[i][1] = zero; }

  if constexpr (FUSE) {
#pragma unroll
    for (int ks = 0; ks < CA / 32; ks++) {
      bf16x8 b0 = *(const bf16x8*)&wnt[(size_t)(colbase + l16) * CA + ks * 32 + quad * 8];
      bf16x8 b1 = *(const bf16x8*)&wnt[(size_t)(colbase + 16 + l16) * CA + ks * 32 + quad * 8];
#pragma unroll
      for (int rt = 0; rt < 4; rt++) {
        bf16x8 a = *(const bf16x8*)&ftile[(rt * 16 + l16) * FSTR + ks * 32 + quad * 8];
        acc[rt][0] = __builtin_amdgcn_mfma_f32_16x16x32_bf16(a, b0, acc[rt][0], 0, 0, 0);
        acc[rt][1] = __builtin_amdgcn_mfma_f32_16x16x32_bf16(a, b1, acc[rt][1], 0, 0, 0);
      }
    }
  }

  constexpr int CH = CIN / 8;     // 16B chunks per row
  constexpr int RPP = 256 / CH;   // rows staged per pass

  for (int k = 0; k < KOFF; k++) {
    // gather masked neighbor rows into LDS (zeros when masked out)
#pragma unroll
    for (int p = 0; p < TR / RPP; p++) {
      int r = p * RPP + t / CH;
      int ch = (t % CH) * 8;
      u32x4 v = {0, 0, 0, 0};
      if (r < nrows && ((lmb[r] >> k) & 1u)) {
        int nb = lnbr[r * KOFF + k];
        v = *(const u32x4*)&hin[(size_t)nb * CIN + ch];
      }
      *(u32x4*)&tile[r * STR + ch] = v;
    }
    __syncthreads();
    const unsigned short* wk = wt + (size_t)k * CB * CIN;
#pragma unroll
    for (int ks = 0; ks < CIN / 32; ks++) {
      bf16x8 b0 = *(const bf16x8*)&wk[(size_t)(colbase + l16) * CIN + ks * 32 + quad * 8];
      bf16x8 b1 = *(const bf16x8*)&wk[(size_t)(colbase + 16 + l16) * CIN + ks * 32 + quad * 8];
#pragma unroll
      for (int rt = 0; rt < 4; rt++) {
        bf16x8 a = *(const bf16x8*)&tile[(rt * 16 + l16) * STR + ks * 32 + quad * 8];
        acc[rt][0] = __builtin_amdgcn_mfma_f32_16x16x32_bf16(a, b0, acc[rt][0], 0, 0, 0);
        acc[rt][1] = __builtin_amdgcn_mfma_f32_16x16x32_bf16(a, b1, acc[rt][1], 0, 0, 0);
      }
    }
    __syncthreads();
  }

  // epilogue: C/D layout col=lane&15, row=(lane>>4)*4+reg  [guide §3, m89-verified]
#pragma unroll
  for (int rt = 0; rt < 4; rt++) {
#pragma unroll
    for (int ct = 0; ct < 2; ct++) {
#pragma unroll
      for (int i = 0; i < 4; i++) {
        int r = rt * 16 + quad * 4 + i;
        if (r < nrows) {
          int c = colbase + ct * 16 + l16;
          out[(size_t)(rowbase + r) * CB + c] = acc[rt][ct][i];
        }
      }
    }
  }
}

extern "C" void kernel_launch(void* const* d_in, const int* in_sizes, int n_in,
                              void* d_out, int out_size, void* d_ws, size_t ws_size,
                              hipStream_t stream) {
  const float* feat   = (const float*)d_in[0];
  const float* gamma1 = (const float*)d_in[1];
  const float* beta1  = (const float*)d_in[2];
  const float* W1     = (const float*)d_in[3];
  const float* gamma2 = (const float*)d_in[4];
  const float* beta2  = (const float*)d_in[5];
  const float* W2     = (const float*)d_in[6];
  const float* Wnin   = (const float*)d_in[7];
  const int*   nbr    = (const int*)d_in[8];
  const void*  mask   = d_in[9];
  float* out = (float*)d_out;

  const int n = in_sizes[0] / CA;  // 100000

  // workspace layout (~104 MB total)
  char* ws = (char*)d_ws;
  size_t off = 0;
  auto alloc = [&](size_t bytes) { size_t p = off; off += (bytes + 255) & ~(size_t)255; return p; };
  int*            flag  = (int*)           (ws + alloc(256));
  float*          sums1 = (float*)         (ws + alloc(2 * CA * 4));   // ends at 768
  float*          sums2 = (float*)         (ws + alloc(2 * CB * 4));   // ends at 1792
  float*          sc1   = (float*)         (ws + alloc(2 * CA * 4));
  float*          sc2   = (float*)         (ws + alloc(2 * CB * 4));
  uint32_t*       mbits = (uint32_t*)      (ws + alloc((size_t)n * 4));
  unsigned short* fb    = (unsigned short*)(ws + alloc((size_t)n * CA * 2));
  unsigned short* hb1   = (unsigned short*)(ws + alloc((size_t)n * CA * 2));
  float*          out1  = (float*)         (ws + alloc((size_t)n * CB * 4));
  unsigned short* hb2   = (unsigned short*)(ws + alloc((size_t)n * CB * 2));
  unsigned short* w1t   = (unsigned short*)(ws + alloc((size_t)KOFF * CB * CA * 2));
  unsigned short* w2t   = (unsigned short*)(ws + alloc((size_t)KOFF * CB * CB * 2));
  unsigned short* wnt   = (unsigned short*)(ws + alloc((size_t)CB * CA * 2));

  // zero flag + stats accumulators (ws is poisoned 0xAA before every launch)
  hipMemsetAsync(d_ws, 0, 1792, stream);

  // mask decode + pack
  detect_mask_k<<<1, 256, 0, stream>>>((const unsigned char*)mask, flag);
  pack_mask_k<<<(n + 255) / 256, 256, 0, stream>>>(mask, flag, mbits, n);

  // weight transpose/convert
  {
    int t1 = KOFF * CA * CB, t2 = KOFF * CB * CB, t3 = CA * CB;
    transpose_w_k<<<(t1 + 255) / 256, 256, 0, stream>>>(W1, w1t, KOFF, CA, CB);
    transpose_w_k<<<(t2 + 255) / 256, 256, 0, stream>>>(W2, w2t, KOFF, CB, CB);
    transpose_w_k<<<(t3 + 255) / 256, 256, 0, stream>>>(Wnin, wnt, 1, CA, CB);
  }

  // stage 1: BN stats on feat -> scale/shift -> h1 (bn+relu bf16) + raw feat bf16
  col_stats_k<CA><<<256, 256, 0, stream>>>(feat, n, sums1);
  bn_finalize_k<CA><<<1, CA, 0, stream>>>(sums1, gamma1, beta1, sc1, n);
  bn_apply_k<CA, true><<<(n * CA / 4 + 255) / 256, 256, 0, stream>>>(feat, sc1, hb1, fb, n * CA);

  // conv1: out1 = subconv(h1, W1)  [N,128] fp32
  conv_k<CA, false><<<(n + 63) / 64, 256, 0, stream>>>(hb1, w1t, nbr, mbits, nullptr, nullptr, out1, n);

  // stage 2: BN stats on out1 -> h2 (bn+relu bf16)
  col_stats_k<CB><<<256, 256, 0, stream>>>(out1, n, sums2);
  bn_finalize_k<CB><<<1, CB, 0, stream>>>(sums2, gamma2, beta2, sc2, n);
  bn_apply_k<CB, false><<<(n * CB / 4 + 255) / 256, 256, 0, stream>>>(out1, sc2, hb2, nullptr, n * CB);

  // conv2 + fused NiN shortcut: out = feat@Wnin + subconv(h2, W2)
  conv_k<CB, true><<<(n + 63) / 64, 256, 0, stream>>>(hb2, w2t, nbr, mbits, fb, wnt, out, n);
}

// Round 2
// 531.091 us; speedup vs baseline: 1.1421x; 1.1421x over previous
//
#include <hip/hip_runtime.h>
#include <stdint.h>

#define CA 64     // in channels
#define CB 128    // out channels
#define KOFF 27   // 3^3 offsets
#define BN_EPS 1e-4f

typedef short bf16x8 __attribute__((ext_vector_type(8)));
typedef float f32x4 __attribute__((ext_vector_type(4)));
typedef unsigned int u32x4 __attribute__((ext_vector_type(4)));
typedef unsigned short u16x4 __attribute__((ext_vector_type(4)));

__device__ __forceinline__ unsigned short f2bf(float f) {
  union { float f; uint32_t u; } c; c.f = f;
  uint32_t u = c.u;
  return (unsigned short)((u + 0x7FFFu + ((u >> 16) & 1u)) >> 16);  // RNE
}

// Barrier WITHOUT vmcnt drain: LDS visibility only. Safe because all cross-wave
// data flows through LDS (ds_write -> lgkmcnt(0) -> s_barrier); in-flight global
// loads target VGPRs only and must stay in flight (that's the pipeline).
__device__ __forceinline__ void barrier_lds() {
  asm volatile("s_waitcnt lgkmcnt(0)\n\ts_barrier" ::: "memory");
}

// ---- mask dtype detection: if int32 layout, bytes at i%4!=0 are all zero ----
__global__ void detect_mask_k(const unsigned char* __restrict__ m, int* flag) {
  unsigned v = 0;
  for (int i = threadIdx.x; i < 4096; i += 256)
    if (i & 3) v |= m[i];
  if (v) atomicOr(flag, 1);   // 1 => byte/bool layout, 0 => int32 layout
}

__global__ void pack_mask_k(const void* __restrict__ mp, const int* __restrict__ flag,
                            uint32_t* __restrict__ bits, int n) {
  int i = blockIdx.x * blockDim.x + threadIdx.x;
  if (i >= n) return;
  uint32_t b = 0;
  if (*flag) {
    const unsigned char* m = (const unsigned char*)mp + (size_t)i * KOFF;
    for (int k = 0; k < KOFF; k++) b |= (m[k] ? 1u : 0u) << k;
  } else {
    const int* m = (const int*)mp + (size_t)i * KOFF;
    for (int k = 0; k < KOFF; k++) b |= (m[k] ? 1u : 0u) << k;
  }
  bits[i] = b;
}

// ---- all weight transposes + bf16 convert in one launch ----
// wt[k][co][ci] = bf16(w[k][ci][co])
__global__ void transpose_all_k(const float* __restrict__ W1, const float* __restrict__ W2,
                                const float* __restrict__ Wnin,
                                unsigned short* __restrict__ w1t, unsigned short* __restrict__ w2t,
                                unsigned short* __restrict__ wnt) {
  const int t1 = KOFF * CA * CB, t2 = KOFF * CB * CB, t3 = CA * CB;
  int idx = blockIdx.x * blockDim.x + threadIdx.x;
  if (idx < t1) {
    int ci = idx % CA; int r = idx / CA; int co = r % CB; int k = r / CB;
    w1t[idx] = f2bf(W1[((size_t)k * CA + ci) * CB + co]);
  } else if (idx < t1 + t2) {
    int j = idx - t1;
    int ci = j % CB; int r = j / CB; int co = r % CB; int k = r / CB;
    w2t[j] = f2bf(W2[((size_t)k * CB + ci) * CB + co]);
  } else if (idx < t1 + t2 + t3) {
    int j = idx - t1 - t2;
    int ci = j % CA; int co = j / CA;
    wnt[j] = f2bf(Wnin[(size_t)ci * CB + co]);
  }
}

// ---- per-channel sum & sumsq (training-mode BN stats) ----
template<int C>
__global__ void col_stats_k(const float* __restrict__ x, int n, float* __restrict__ sums) {
  __shared__ float ssum[C], ssq[C];
  int t = threadIdx.x;
  for (int i = t; i < C; i += 256) { ssum[i] = 0.f; ssq[i] = 0.f; }
  __syncthreads();
  const int c = t % C;
  const int rpb = 256 / C;
  float s = 0.f, q = 0.f;
  for (int r = blockIdx.x * rpb + t / C; r < n; r += gridDim.x * rpb) {
    float v = x[(size_t)r * C + c];
    s += v; q += v * v;
  }
  atomicAdd(&ssum[c], s);
  atomicAdd(&ssq[c], q);
  __syncthreads();
  for (int i = t; i < C; i += 256) {
    atomicAdd(&sums[i], ssum[i]);
    atomicAdd(&sums[C + i], ssq[i]);
  }
}

template<int C>
__global__ void bn_finalize_k(const float* __restrict__ sums, const float* __restrict__ gamma,
                              const float* __restrict__ beta, float* __restrict__ sc, int n) {
  int c = threadIdx.x;
  if (c >= C) return;
  float inv_n = 1.f / (float)n;
  float mean = sums[c] * inv_n;
  float var = sums[C + c] * inv_n - mean * mean;
  float rstd = rsqrtf(var + BN_EPS);
  float scale = gamma[c] * rstd;
  sc[c] = scale;
  sc[C + c] = beta[c] - mean * scale;
}

template<int C, bool RAW>
__global__ void bn_apply_k(const float* __restrict__ x, const float* __restrict__ sc,
                           unsigned short* __restrict__ h, unsigned short* __restrict__ raw,
                           int total) {
  int idx = (blockIdx.x * blockDim.x + threadIdx.x) * 4;
  if (idx >= total) return;
  f32x4 v = *(const f32x4*)&x[idx];
  int c0 = idx % C;
  u16x4 ho, ro;
#pragma unroll
  for (int j = 0; j < 4; j++) {
    float s = sc[c0 + j], b = sc[C + c0 + j];
    float hv = fmaxf(v[j] * s + b, 0.f);
    ho[j] = f2bf(hv);
    if (RAW) ro[j] = f2bf(v[j]);
  }
  *(u16x4*)&h[idx] = ho;
  if (RAW) *(u16x4*)&raw[idx] = ro;
}

// ---- pipelined gather-GEMM subconv ----
// out[n,:] = sum_k mask[n,k] * hin[nbr[n,k],:] @ W[k]   (+ FUSE: fbraw @ wnt)
// Block: 64 rows x 128 cols, 256 threads (4 waves of 64x32).
// Software pipeline: gathers for k+2 and B-frags for k+2 prefetched into VGPRs,
// double-buffered LDS tile, single lgkmcnt-only barrier per iteration so global
// loads stay in flight across the barrier.
template<int CIN, bool FUSE>
__launch_bounds__(256)
__global__ void conv_k(const unsigned short* __restrict__ hin,
                       const unsigned short* __restrict__ wt,
                       const int* __restrict__ nbr,
                       const uint32_t* __restrict__ mbits,
                       const unsigned short* __restrict__ fbraw,
                       const unsigned short* __restrict__ wnt,
                       float* __restrict__ out, int n) {
  constexpr int TR = 64;
  constexpr int STR = CIN + 8;      // +16B pad breaks LDS bank alias across rows
  constexpr int FSTR = CA + 8;
  constexpr int NKS = CIN / 32;     // MFMA K-steps per offset (2 or 4)
  constexpr int CH = CIN / 8;       // 16B chunks per row
  constexpr int NP = TR * CH / 256; // staging passes per thread

  __shared__ alignas(16) unsigned short tile[2][TR * STR];
  __shared__ alignas(16) unsigned short ftile[FUSE ? TR * FSTR : 16];
  __shared__ int lnbr[TR * KOFF];
  __shared__ uint32_t lmb[TR];

  const int t = threadIdx.x;
  const int rowbase = blockIdx.x * TR;
  const int nrows = min(TR, n - rowbase);

  for (int i = t; i < nrows * KOFF; i += 256) lnbr[i] = nbr[(size_t)rowbase * KOFF + i];
  if (t < TR) lmb[t] = (t < nrows) ? mbits[rowbase + t] : 0u;

  if constexpr (FUSE) {
#pragma unroll
    for (int p = 0; p < 2; p++) {
      int r = p * 32 + (t >> 3);
      int ch = (t & 7) * 8;
      u32x4 v = {0, 0, 0, 0};
      if (r < nrows) v = *(const u32x4*)&fbraw[(size_t)(rowbase + r) * CA + ch];
      *(u32x4*)&ftile[r * FSTR + ch] = v;
    }
  }
  __syncthreads();  // lnbr/lmb/ftile visible (full drain fine here)

  const int lane = t & 63;
  const int wave = t >> 6;
  const int l16 = lane & 15;
  const int quad = lane >> 4;
  const int colbase = wave * 32;
  const int goff = (t % CH) * 8;    // channel offset within row (shorts)
  const int grow = t / CH;          // row within a staging pass
  const int boff0 = (colbase + l16) * CIN + quad * 8;
  const int boff1 = boff0 + 16 * CIN;

  f32x4 acc[4][2];
#pragma unroll
  for (int i = 0; i < 4; i++) { acc[i][0] = f32x4{0,0,0,0}; acc[i][1] = f32x4{0,0,0,0}; }

  bf16x8 bfr[2][2 * NKS];
  u32x4 gr[NP];

  // ---- prologue: b(0), g(0)->tile[0], b(1), g(1) pending ----
#pragma unroll
  for (int ks = 0; ks < NKS; ks++) {
    bfr[0][2 * ks]     = *(const bf16x8*)&wt[boff0 + ks * 32];
    bfr[0][2 * ks + 1] = *(const bf16x8*)&wt[boff1 + ks * 32];
  }
#pragma unroll
  for (int p = 0; p < NP; p++) {
    int r = p * (256 / CH) + grow;
    u32x4 v = {0, 0, 0, 0};
    if (r < nrows && (lmb[r] & 1u)) v = *(const u32x4*)&hin[(size_t)lnbr[r * KOFF] * CIN + goff];
    gr[p] = v;
  }
#pragma unroll
  for (int p = 0; p < NP; p++) {
    int r = p * (256 / CH) + grow;
    *(u32x4*)&tile[0][r * STR + goff] = gr[p];
  }
  {
    const unsigned short* wk = wt + (size_t)1 * CB * CIN;
#pragma unroll
    for (int ks = 0; ks < NKS; ks++) {
      bfr[1][2 * ks]     = *(const bf16x8*)&wk[boff0 + ks * 32];
      bfr[1][2 * ks + 1] = *(const bf16x8*)&wk[boff1 + ks * 32];
    }
  }
#pragma unroll
  for (int p = 0; p < NP; p++) {
    int r = p * (256 / CH) + grow;
    u32x4 v = {0, 0, 0, 0};
    if (r < nrows && ((lmb[r] >> 1) & 1u))
      v = *(const u32x4*)&hin[(size_t)lnbr[r * KOFF + 1] * CIN + goff];
    gr[p] = v;
  }

  if constexpr (FUSE) {
    // NiN shortcut: acc += ftile @ wnt  (K = CA)
#pragma unroll
    for (int ks = 0; ks < CA / 32; ks++) {
      bf16x8 b0 = *(const bf16x8*)&wnt[(colbase + l16) * CA + ks * 32 + quad * 8];
      bf16x8 b1 = *(const bf16x8*)&wnt[(colbase + 16 + l16) * CA + ks * 32 + quad * 8];
#pragma unroll
      for (int rt = 0; rt < 4; rt++) {
        bf16x8 a = *(const bf16x8*)&ftile[(rt * 16 + l16) * FSTR + ks * 32 + quad * 8];
        acc[rt][0] = __builtin_amdgcn_mfma_f32_16x16x32_bf16(a, b0, acc[rt][0], 0, 0, 0);
        acc[rt][1] = __builtin_amdgcn_mfma_f32_16x16x32_bf16(a, b1, acc[rt][1], 0, 0, 0);
      }
    }
  }
  barrier_lds();  // tile[0] visible; g(1)/b(1) stay in flight

  // ---- main loop, fully unrolled so k&1 buffers fold to registers ----
#pragma unroll
  for (int k = 0; k < KOFF; k++) {
    const int cur = k & 1, nxt = cur ^ 1;
#pragma unroll
    for (int ks = 0; ks < NKS; ks++) {
#pragma unroll
      for (int rt = 0; rt < 4; rt++) {
        bf16x8 a = *(const bf16x8*)&tile[cur][(rt * 16 + l16) * STR + ks * 32 + quad * 8];
        acc[rt][0] = __builtin_amdgcn_mfma_f32_16x16x32_bf16(a, bfr[cur][2 * ks],     acc[rt][0], 0, 0, 0);
        acc[rt][1] = __builtin_amdgcn_mfma_f32_16x16x32_bf16(a, bfr[cur][2 * ks + 1], acc[rt][1], 0, 0, 0);
      }
    }
    if (k + 2 < KOFF) {  // b-frags for k+2 into the regs this MFMA just consumed
      const unsigned short* wk = wt + (size_t)(k + 2) * CB * CIN;
#pragma unroll
      for (int ks = 0; ks < NKS; ks++) {
        bfr[cur][2 * ks]     = *(const bf16x8*)&wk[boff0 + ks * 32];
        bfr[cur][2 * ks + 1] = *(const bf16x8*)&wk[boff1 + ks * 32];
      }
    }
    if (k + 1 < KOFF) {
#pragma unroll
      for (int p = 0; p < NP; p++) {  // store g(k+1): waits only loads >= 1 iter old
        int r = p * (256 / CH) + grow;
        *(u32x4*)&tile[nxt][r * STR + goff] = gr[p];
      }
      if (k + 2 < KOFF) {
#pragma unroll
        for (int p = 0; p < NP; p++) {
          int r = p * (256 / CH) + grow;
          u32x4 v = {0, 0, 0, 0};
          if (r < nrows && ((lmb[r] >> (k + 2)) & 1u))
            v = *(const u32x4*)&hin[(size_t)lnbr[r * KOFF + k + 2] * CIN + goff];
          gr[p] = v;
        }
      }
      barrier_lds();
    }
  }

  // epilogue: C/D layout col=lane&15, row=(lane>>4)*4+reg
#pragma unroll
  for (int rt = 0; rt < 4; rt++) {
#pragma unroll
    for (int ct = 0; ct < 2; ct++) {
#pragma unroll
      for (int i = 0; i < 4; i++) {
        int r = rt * 16 + quad * 4 + i;
        if (r < nrows) {
          int c = colbase + ct * 16 + l16;
          out[(size_t)(rowbase + r) * CB + c] = acc[rt][ct][i];
        }
      }
    }
  }
}

extern "C" void kernel_launch(void* const* d_in, const int* in_sizes, int n_in,
                              void* d_out, int out_size, void* d_ws, size_t ws_size,
                              hipStream_t stream) {
  const float* feat   = (const float*)d_in[0];
  const float* gamma1 = (const float*)d_in[1];
  const float* beta1  = (const float*)d_in[2];
  const float* W1     = (const float*)d_in[3];
  const float* gamma2 = (const float*)d_in[4];
  const float* beta2  = (const float*)d_in[5];
  const float* W2     = (const float*)d_in[6];
  const float* Wnin   = (const float*)d_in[7];
  const int*   nbr    = (const int*)d_in[8];
  const void*  mask   = d_in[9];
  float* out = (float*)d_out;

  const int n = in_sizes[0] / CA;  // 100000

  char* ws = (char*)d_ws;
  size_t off = 0;
  auto alloc = [&](size_t bytes) { size_t p = off; off += (bytes + 255) & ~(size_t)255; return p; };
  int*            flag  = (int*)           (ws + alloc(256));
  float*          sums1 = (float*)         (ws + alloc(2 * CA * 4));
  float*          sums2 = (float*)         (ws + alloc(2 * CB * 4));
  float*          sc1   = (float*)         (ws + alloc(2 * CA * 4));
  float*          sc2   = (float*)         (ws + alloc(2 * CB * 4));
  uint32_t*       mbits = (uint32_t*)      (ws + alloc((size_t)n * 4));
  unsigned short* fb    = (unsigned short*)(ws + alloc((size_t)n * CA * 2));
  unsigned short* hb1   = (unsigned short*)(ws + alloc((size_t)n * CA * 2));
  float*          out1  = (float*)         (ws + alloc((size_t)n * CB * 4));
  unsigned short* hb2   = (unsigned short*)(ws + alloc((size_t)n * CB * 2));
  unsigned short* w1t   = (unsigned short*)(ws + alloc((size_t)KOFF * CB * CA * 2));
  unsigned short* w2t   = (unsigned short*)(ws + alloc((size_t)KOFF * CB * CB * 2));
  unsigned short* wnt   = (unsigned short*)(ws + alloc((size_t)CB * CA * 2));

  // zero flag + stats accumulators (ws is poisoned 0xAA before every launch)
  hipMemsetAsync(d_ws, 0, 1792, stream);

  detect_mask_k<<<1, 256, 0, stream>>>((const unsigned char*)mask, flag);
  pack_mask_k<<<(n + 255) / 256, 256, 0, stream>>>(mask, flag, mbits, n);

  {
    int tot = KOFF * CA * CB + KOFF * CB * CB + CA * CB;
    transpose_all_k<<<(tot + 255) / 256, 256, 0, stream>>>(W1, W2, Wnin, w1t, w2t, wnt);
  }

  // stage 1: BN stats -> scale/shift -> h1 (bn+relu bf16) + raw feat bf16
  col_stats_k<CA><<<256, 256, 0, stream>>>(feat, n, sums1);
  bn_finalize_k<CA><<<1, CA, 0, stream>>>(sums1, gamma1, beta1, sc1, n);
  bn_apply_k<CA, true><<<(n * CA / 4 + 255) / 256, 256, 0, stream>>>(feat, sc1, hb1, fb, n * CA);

  // conv1: out1 = subconv(h1, W1)  [N,128] fp32
  conv_k<CA, false><<<(n + 63) / 64, 256, 0, stream>>>(hb1, w1t, nbr, mbits, nullptr, nullptr, out1, n);

  // stage 2
  col_stats_k<CB><<<256, 256, 0, stream>>>(out1, n, sums2);
  bn_finalize_k<CB><<<1, CB, 0, stream>>>(sums2, gamma2, beta2, sc2, n);
  bn_apply_k<CB, false><<<(n * CB / 4 + 255) / 256, 256, 0, stream>>>(out1, sc2, hb2, nullptr, n * CB);

  // conv2 + fused NiN shortcut
  conv_k<CB, true><<<(n + 63) / 64, 256, 0, stream>>>(hb2, w2t, nbr, mbits, fb, wnt, out, n);
}